// Round 3
// baseline (134.803 us; speedup 1.0000x reference)
//
#include <hip/hip_runtime.h>
#include <hip/hip_bf16.h>
#include <hip/hip_fp16.h>
#include <math.h>

// B=4096, D=768, K=60. Output: scalar fp32 mean CE loss, label 0.
// loss_b = logsumexp(logits_b) - logits_b[0].
//
// Round-2 lesson: gather-locality restructuring (plane split) moved the
// total by ~1% -> the region is dominated by fixed costs (dispatch chain
// serialization + re-poison fill) and/or an L3 service-rate floor that is
// insensitive to layout. This version attacks the dispatch chain:
//
//   memsetAsync(out)                                (tiny)
//   1. convert_items_f16: fp32 -> fp16 rows (NT loads on the fp32 stream)
//   2. fused_gather_lse: ONE block (8 waves) per batch row:
//        gather 61 fp16 item rows (16 loads in flight per wave),
//        dot via v_dot2_f32_f16, butterfly fold, logits in LDS,
//        wave-0 logsumexp, single atomicAdd(out, loss/NB).
//
// vs previous: 4 dispatches -> 2 (+memset); no logp round-trip; user row
// re-reads become L1-hits (all 8 slot-waves share one CU).

#define NB 4096
#define ND 768
#define NK 60
#define ND4  (ND / 4)          // 192 float4 per fp32 row
#define NDU  (ND / 2)          // 384 uints per fp16 row
#define NLOGITS (NK + 1)       // 61
#define NPAD 64

#define WS_ITEMS_OFF 0
#define WS_NEED      ((size_t)NB * ND * 2)    // 6.29 MB fp16 table

typedef _Float16 h2 __attribute__((ext_vector_type(2)));
typedef float    f2 __attribute__((ext_vector_type(2)));
typedef float    f4v __attribute__((ext_vector_type(4)));

__device__ __forceinline__ float dot2_acc(unsigned int u, unsigned int v, float c) {
#if __has_builtin(__builtin_amdgcn_fdot2)
    return __builtin_amdgcn_fdot2(__builtin_bit_cast(h2, u),
                                  __builtin_bit_cast(h2, v), c, false);
#else
    f2 a = __builtin_convertvector(__builtin_bit_cast(h2, u), f2);
    f2 b = __builtin_convertvector(__builtin_bit_cast(h2, v), f2);
    return c + a.x * b.x + a.y * b.y;
#endif
}

__device__ __forceinline__ unsigned int pack_h2(float x, float y) {
    h2 h = { (_Float16)x, (_Float16)y };
    return __builtin_bit_cast(unsigned int, h);
}

// Butterfly fold: 8 per-lane partials -> every lane holds the full 64-lane
// sum of logit (lane & 7).  (Verified: absmax 0 in rounds 0/2.)
__device__ __forceinline__ float fold8(const float acc[8], int lane) {
    const int bit0 = lane & 1;
    float n[4];
    #pragma unroll
    for (int j = 0; j < 4; ++j) {
        float mine  = bit0 ? acc[2*j+1] : acc[2*j];
        float other = bit0 ? acc[2*j]   : acc[2*j+1];
        n[j] = mine + __shfl_xor(other, 1, 64);
    }
    const int bit1 = (lane >> 1) & 1;
    float s[2];
    #pragma unroll
    for (int j = 0; j < 2; ++j) {
        float mine  = bit1 ? n[2*j+1] : n[2*j];
        float other = bit1 ? n[2*j]   : n[2*j+1];
        s[j] = mine + __shfl_xor(other, 2, 64);
    }
    const int bit2 = (lane >> 2) & 1;
    float mine  = bit2 ? s[1] : s[0];
    float other = bit2 ? s[0] : s[1];
    float r = mine + __shfl_xor(other, 4, 64);
    r += __shfl_xor(r, 8, 64);
    r += __shfl_xor(r, 16, 64);
    r += __shfl_xor(r, 32, 64);
    return r;
}

// ---- phase 1: items fp32 -> fp16 (packed uint2 = 4 halves) ----
// NT loads: the fp32 stream is single-use; keep it from evicting the fp16
// table (which must stay cache-resident for the gather).
__global__ __launch_bounds__(256) void convert_items_f16(
    const f4v* __restrict__ items, uint2* __restrict__ itemsh)
{
    int i = blockIdx.x * 256 + threadIdx.x;
    f4v v = __builtin_nontemporal_load(items + i);
    uint2 rv;
    rv.x = pack_h2(v.x, v.y);
    rv.y = pack_h2(v.z, v.w);
    itemsh[i] = rv;
}

// ---- phase 2: one block (8 waves) per row; gather + LSE + atomic mean ----
__global__ __launch_bounds__(512, 4) void fused_gather_lse(
    const float* __restrict__ user,
    const unsigned int* __restrict__ itemsh,
    const int* __restrict__ negidx,
    float* __restrict__ out)
{
    const int tid  = threadIdx.x;
    const int lane = tid & 63;
    const int slot = tid >> 6;          // wave id = slot group, 0..7
    const int b    = blockIdx.x;

    // 8 row indices for this wave (wave-uniform -> scalar loads)
    const int* nrow = negidx + (size_t)b * NK;
    int rows[8];
    #pragma unroll
    for (int i = 0; i < 8; ++i) {
        int k = slot * 8 + i;
        rows[i] = (k == 0 || k > NK) ? b : nrow[k - 1];
    }

    // user row fp32 -> packed halves in-register, matching item layout:
    //   ua.{x,y,z,w} = halves of elements 8l..8l+7
    //   ub.{x,y}     = halves of elements 512+4l..512+4l+3
    // All 8 waves read the same 3 KB -> L1-served after first wave.
    const float4* ur4 = (const float4*)(user + (size_t)b * ND);
    float4 uf0 = ur4[2 * lane];
    float4 uf1 = ur4[2 * lane + 1];
    float4 uf2 = ur4[128 + lane];
    uint4 ua;
    ua.x = pack_h2(uf0.x, uf0.y);
    ua.y = pack_h2(uf0.z, uf0.w);
    ua.z = pack_h2(uf1.x, uf1.y);
    ua.w = pack_h2(uf1.z, uf1.w);
    uint2 ub;
    ub.x = pack_h2(uf2.x, uf2.y);
    ub.y = pack_h2(uf2.z, uf2.w);

    // 16 gather loads in flight
    uint4 va[8];
    uint2 vb[8];
    #pragma unroll
    for (int i = 0; i < 8; ++i) {
        const unsigned int* ir = itemsh + (size_t)rows[i] * NDU;
        va[i] = ((const uint4*)ir)[lane];
        vb[i] = ((const uint2*)(ir + 256))[lane];
    }

    float acc[8];
    #pragma unroll
    for (int i = 0; i < 8; ++i) {
        float a = 0.0f;
        a = dot2_acc(ua.x, va[i].x, a);
        a = dot2_acc(ua.y, va[i].y, a);
        a = dot2_acc(ua.z, va[i].z, a);
        a = dot2_acc(ua.w, va[i].w, a);
        a = dot2_acc(ub.x, vb[i].x, a);
        a = dot2_acc(ub.y, vb[i].y, a);
        acc[i] = a;
    }

    float r = fold8(acc, lane);

    __shared__ float lg[NPAD];
    if (lane < 8)
        lg[slot * 8 + lane] = r;
    __syncthreads();

    // wave 0: logsumexp over 61 logits -> one atomic per block
    if (tid < 64) {
        float v  = (tid < NLOGITS) ? lg[tid] : -INFINITY;
        float p0 = lg[0];
        float m = v;
        #pragma unroll
        for (int off = 32; off > 0; off >>= 1)
            m = fmaxf(m, __shfl_down(m, off, 64));
        m = __shfl(m, 0, 64);
        float e = (tid < NLOGITS) ? __expf(v - m) : 0.0f;
        #pragma unroll
        for (int off = 32; off > 0; off >>= 1)
            e += __shfl_down(e, off, 64);
        if (tid == 0) {
            float loss = m + __logf(e) - p0;
            atomicAdd(out, loss * (1.0f / (float)NB));
        }
    }
}

// ---- fallback (fp32 single-kernel path) if ws too small ----
__global__ __launch_bounds__(256) void u2i_loss_f32(
    const float* __restrict__ user,
    const float* __restrict__ items,
    const int* __restrict__ negidx,
    float* __restrict__ out)
{
    const int b    = blockIdx.x;
    const int tid  = threadIdx.x;
    const int wave = tid >> 6;
    const int lane = tid & 63;

    __shared__ int   rows_s[NPAD];
    __shared__ float logits[NPAD];

    if (tid < NPAD) {
        const int* nrow = negidx + (size_t)b * NK;
        rows_s[tid] = (tid == 0 || tid > NK) ? b : nrow[tid - 1];
    }
    const float4* u4 = (const float4*)user + (size_t)b * ND4;
    float4 u0 = u4[lane];
    float4 u1 = u4[64 + lane];
    float4 u2 = u4[128 + lane];
    __syncthreads();

    const float4* it4 = (const float4*)items;
    #pragma unroll
    for (int j = 0; j < 4; ++j) {
        int ks[4];
        const float4* p[4];
        #pragma unroll
        for (int i = 0; i < 4; ++i) {
            ks[i] = wave + j * 16 + i * 4;
            p[i]  = it4 + (size_t)rows_s[ks[i]] * ND4;
        }
        float4 v0[4], v1[4], v2[4];
        #pragma unroll
        for (int i = 0; i < 4; ++i) {
            v0[i] = p[i][lane];
            v1[i] = p[i][64 + lane];
            v2[i] = p[i][128 + lane];
        }
        float acc[4];
        #pragma unroll
        for (int i = 0; i < 4; ++i) {
            float a;
            a  = u0.x * v0[i].x + u0.y * v0[i].y + u0.z * v0[i].z + u0.w * v0[i].w;
            a += u1.x * v1[i].x + u1.y * v1[i].y + u1.z * v1[i].z + u1.w * v1[i].w;
            a += u2.x * v2[i].x + u2.y * v2[i].y + u2.z * v2[i].z + u2.w * v2[i].w;
            acc[i] = a;
        }
        #pragma unroll
        for (int off = 32; off > 0; off >>= 1) {
            #pragma unroll
            for (int i = 0; i < 4; ++i)
                acc[i] += __shfl_down(acc[i], off, 64);
        }
        if (lane == 0) {
            #pragma unroll
            for (int i = 0; i < 4; ++i)
                logits[ks[i]] = acc[i];
        }
    }
    __syncthreads();

    if (tid < 64) {
        float v = (tid < NLOGITS) ? logits[tid] : -INFINITY;
        float m = v;
        #pragma unroll
        for (int off = 32; off > 0; off >>= 1)
            m = fmaxf(m, __shfl_down(m, off, 64));
        m = __shfl(m, 0, 64);
        float e = (tid < NLOGITS) ? __expf(v - m) : 0.0f;
        #pragma unroll
        for (int off = 32; off > 0; off >>= 1)
            e += __shfl_down(e, off, 64);
        if (tid == 0) {
            float loss = m + __logf(e) - logits[0];
            atomicAdd(out, loss * (1.0f / (float)NB));
        }
    }
}

extern "C" void kernel_launch(void* const* d_in, const int* in_sizes, int n_in,
                              void* d_out, int out_size, void* d_ws, size_t ws_size,
                              hipStream_t stream) {
    const float* user  = (const float*)d_in[0];   // (B, D) fp32
    const float* items = (const float*)d_in[1];   // (B, D) fp32
    const int*   negi  = (const int*)d_in[2];     // (B, K) int32
    float* out = (float*)d_out;                   // scalar fp32

    hipMemsetAsync(out, 0, sizeof(float), stream);

    if (ws_size >= WS_NEED) {
        unsigned int* itemsh = (unsigned int*)((char*)d_ws + WS_ITEMS_OFF);

        // 786432 float4 -> 3072 blocks of 256
        convert_items_f16<<<(NB * ND / 4) / 256, 256, 0, stream>>>(
            (const f4v*)items, (uint2*)itemsh);
        // one 8-wave block per row; gather + LSE + atomic mean
        fused_gather_lse<<<NB, 512, 0, stream>>>(
            user, itemsh, negi, out);
    } else {
        u2i_loss_f32<<<NB, 256, 0, stream>>>(user, items, negi, out);
    }
}

// Round 4
// 106.537 us; speedup vs baseline: 1.2653x; 1.2653x over previous
//
#include <hip/hip_runtime.h>
#include <hip/hip_bf16.h>
#include <hip/hip_fp16.h>
#include <math.h>

// B=4096, D=768, K=60. Output: scalar fp32 mean CE loss, label 0.
// loss_b = logsumexp(logits_b) - logits_b[0].
//
// Round-3 lessons (measured):
//  * 4096 same-address atomicAdds serialized ~60us -> per-block partials,
//    16 atomics total (Guideline 12).
//  * gather VGPR_Count=36 < 48 regs of load data => compiler was sinking
//    loads below dots (only ~4-6KB in flight/wave). Fix: issue ALL loads,
//    then __builtin_amdgcn_sched_barrier(0) so no dot can float above a
//    load issue. Target ~80 VGPR, 12KB in flight per wave.
//
// Phases:
//   memsetAsync(out)
//   1. convert_items_f16: fp32 -> fp16 rows (NT loads on fp32 stream)
//   2. gather_dots: one wave per 8 logits, 4 waves/block, decoupled
//      (no barrier, no atomic); logits -> ws
//   3. lse_reduce: 16 blocks x 256 thr; thread = row; per-block LDS
//      reduce -> 16 atomicAdds

#define NB 4096
#define ND 768
#define NK 60
#define ND4  (ND / 4)          // 192 float4 per fp32 row
#define NDU  (ND / 2)          // 384 uints per fp16 row
#define NLOGITS (NK + 1)       // 61
#define NPAD 64

#define WS_LOGITS_OFF 0
#define WS_ITEMS_OFF  ((size_t)NB * NPAD * 4)                   // 1 MB
#define WS_NEED       (WS_ITEMS_OFF + (size_t)NB * ND * 2)      // +6.29 MB

typedef _Float16 h2 __attribute__((ext_vector_type(2)));
typedef float    f2 __attribute__((ext_vector_type(2)));
typedef float    f4v __attribute__((ext_vector_type(4)));

__device__ __forceinline__ float dot2_acc(unsigned int u, unsigned int v, float c) {
#if __has_builtin(__builtin_amdgcn_fdot2)
    return __builtin_amdgcn_fdot2(__builtin_bit_cast(h2, u),
                                  __builtin_bit_cast(h2, v), c, false);
#else
    f2 a = __builtin_convertvector(__builtin_bit_cast(h2, u), f2);
    f2 b = __builtin_convertvector(__builtin_bit_cast(h2, v), f2);
    return c + a.x * b.x + a.y * b.y;
#endif
}

__device__ __forceinline__ unsigned int pack_h2(float x, float y) {
    h2 h = { (_Float16)x, (_Float16)y };
    return __builtin_bit_cast(unsigned int, h);
}

// Butterfly fold: 8 per-lane partials -> every lane holds the full 64-lane
// sum of logit (lane & 7).  (Verified: absmax 0 in rounds 0/2/3.)
__device__ __forceinline__ float fold8(const float acc[8], int lane) {
    const int bit0 = lane & 1;
    float n[4];
    #pragma unroll
    for (int j = 0; j < 4; ++j) {
        float mine  = bit0 ? acc[2*j+1] : acc[2*j];
        float other = bit0 ? acc[2*j]   : acc[2*j+1];
        n[j] = mine + __shfl_xor(other, 1, 64);
    }
    const int bit1 = (lane >> 1) & 1;
    float s[2];
    #pragma unroll
    for (int j = 0; j < 2; ++j) {
        float mine  = bit1 ? n[2*j+1] : n[2*j];
        float other = bit1 ? n[2*j]   : n[2*j+1];
        s[j] = mine + __shfl_xor(other, 2, 64);
    }
    const int bit2 = (lane >> 2) & 1;
    float mine  = bit2 ? s[1] : s[0];
    float other = bit2 ? s[0] : s[1];
    float r = mine + __shfl_xor(other, 4, 64);
    r += __shfl_xor(r, 8, 64);
    r += __shfl_xor(r, 16, 64);
    r += __shfl_xor(r, 32, 64);
    return r;
}

// ---- phase 1: items fp32 -> fp16 (packed uint2 = 4 halves) ----
__global__ __launch_bounds__(256) void convert_items_f16(
    const f4v* __restrict__ items, uint2* __restrict__ itemsh)
{
    int i = blockIdx.x * 256 + threadIdx.x;
    f4v v = __builtin_nontemporal_load(items + i);
    uint2 rv;
    rv.x = pack_h2(v.x, v.y);
    rv.y = pack_h2(v.z, v.w);
    itemsh[i] = rv;
}

// ---- phase 2: one wave per 8 logits; 8 waves per row; decoupled ----
__global__ __launch_bounds__(256) void gather_dots(
    const float* __restrict__ user,
    const unsigned int* __restrict__ itemsh,
    const int* __restrict__ negidx,
    float* __restrict__ logits)
{
    const int tid  = threadIdx.x;
    const int lane = tid & 63;
    const int w    = blockIdx.x * 4 + (tid >> 6);   // global wave id
    const int b    = w >> 3;                        // row
    const int slot = w & 7;                         // 8 logits per slot

    // Issue user-row loads FIRST (their latency hides under index setup).
    const float4* ur4 = (const float4*)(user + (size_t)b * ND);
    float4 uf0 = ur4[2 * lane];        // elements 8l..8l+3
    float4 uf1 = ur4[2 * lane + 1];    // elements 8l+4..8l+7
    float4 uf2 = ur4[128 + lane];      // elements 512+4l..512+4l+3

    // 8 row indices (wave-uniform -> scalar loads)
    const int* nrow = negidx + (size_t)b * NK;
    int rows[8];
    #pragma unroll
    for (int i = 0; i < 8; ++i) {
        int k = slot * 8 + i;
        rows[i] = (k == 0 || k > NK) ? b : nrow[k - 1];
    }

    // Issue ALL 16 gather loads; sched_barrier(0) pins them above any
    // consumer so the register allocator cannot issue-serialize them.
    uint4 va[8];
    uint2 vb[8];
    #pragma unroll
    for (int i = 0; i < 8; ++i) {
        const unsigned int* ir = itemsh + (size_t)rows[i] * NDU;
        va[i] = ((const uint4*)ir)[lane];
        vb[i] = ((const uint2*)(ir + 256))[lane];
    }
    __builtin_amdgcn_sched_barrier(0);

    // Pack user row to halves (needs only uf*; gathers stay in flight).
    uint4 ua;
    ua.x = pack_h2(uf0.x, uf0.y);
    ua.y = pack_h2(uf0.z, uf0.w);
    ua.z = pack_h2(uf1.x, uf1.y);
    ua.w = pack_h2(uf1.z, uf1.w);
    uint2 ub;
    ub.x = pack_h2(uf2.x, uf2.y);
    ub.y = pack_h2(uf2.z, uf2.w);

    float acc[8];
    #pragma unroll
    for (int i = 0; i < 8; ++i) {
        float a = 0.0f;
        a = dot2_acc(ua.x, va[i].x, a);
        a = dot2_acc(ua.y, va[i].y, a);
        a = dot2_acc(ua.z, va[i].z, a);
        a = dot2_acc(ua.w, va[i].w, a);
        a = dot2_acc(ub.x, vb[i].x, a);
        a = dot2_acc(ub.y, vb[i].y, a);
        acc[i] = a;
    }

    float r = fold8(acc, lane);
    if (lane < 8)
        logits[(size_t)b * NPAD + slot * 8 + lane] = r;
}

// ---- phase 3: thread = row; per-block partial; 16 atomics total ----
__global__ __launch_bounds__(256) void lse_reduce(
    const float* __restrict__ logits, float* __restrict__ out)
{
    const int tid = threadIdx.x;
    const int b   = blockIdx.x * 256 + tid;

    const float4* lr = (const float4*)(logits + (size_t)b * NPAD);
    float4 v[16];
    #pragma unroll
    for (int j = 0; j < 16; ++j)
        v[j] = lr[j];

    // valid logits: elements 0..60  (v[15].x is element 60)
    float m = v[0].x;
    #pragma unroll
    for (int j = 0; j < 15; ++j)
        m = fmaxf(m, fmaxf(fmaxf(v[j].x, v[j].y), fmaxf(v[j].z, v[j].w)));
    m = fmaxf(m, v[15].x);

    float e = 0.0f;
    #pragma unroll
    for (int j = 0; j < 15; ++j)
        e += __expf(v[j].x - m) + __expf(v[j].y - m) +
             __expf(v[j].z - m) + __expf(v[j].w - m);
    e += __expf(v[15].x - m);

    float loss = m + __logf(e) - v[0].x;

    #pragma unroll
    for (int off = 32; off > 0; off >>= 1)
        loss += __shfl_down(loss, off, 64);

    __shared__ float ps[4];
    if ((tid & 63) == 0) ps[tid >> 6] = loss;
    __syncthreads();
    if (tid == 0)
        atomicAdd(out, (ps[0] + ps[1] + ps[2] + ps[3]) * (1.0f / (float)NB));
}

// ---- fallback (fp32 single-kernel path) if ws too small ----
__global__ __launch_bounds__(256) void u2i_loss_f32(
    const float* __restrict__ user,
    const float* __restrict__ items,
    const int* __restrict__ negidx,
    float* __restrict__ out)
{
    const int b    = blockIdx.x;
    const int tid  = threadIdx.x;
    const int wave = tid >> 6;
    const int lane = tid & 63;

    __shared__ int   rows_s[NPAD];
    __shared__ float logits[NPAD];

    if (tid < NPAD) {
        const int* nrow = negidx + (size_t)b * NK;
        rows_s[tid] = (tid == 0 || tid > NK) ? b : nrow[tid - 1];
    }
    const float4* u4 = (const float4*)user + (size_t)b * ND4;
    float4 u0 = u4[lane];
    float4 u1 = u4[64 + lane];
    float4 u2 = u4[128 + lane];
    __syncthreads();

    const float4* it4 = (const float4*)items;
    #pragma unroll
    for (int j = 0; j < 4; ++j) {
        int ks[4];
        const float4* p[4];
        #pragma unroll
        for (int i = 0; i < 4; ++i) {
            ks[i] = wave + j * 16 + i * 4;
            p[i]  = it4 + (size_t)rows_s[ks[i]] * ND4;
        }
        float4 v0[4], v1[4], v2[4];
        #pragma unroll
        for (int i = 0; i < 4; ++i) {
            v0[i] = p[i][lane];
            v1[i] = p[i][64 + lane];
            v2[i] = p[i][128 + lane];
        }
        float acc[4];
        #pragma unroll
        for (int i = 0; i < 4; ++i) {
            float a;
            a  = u0.x * v0[i].x + u0.y * v0[i].y + u0.z * v0[i].z + u0.w * v0[i].w;
            a += u1.x * v1[i].x + u1.y * v1[i].y + u1.z * v1[i].z + u1.w * v1[i].w;
            a += u2.x * v2[i].x + u2.y * v2[i].y + u2.z * v2[i].z + u2.w * v2[i].w;
            acc[i] = a;
        }
        #pragma unroll
        for (int off = 32; off > 0; off >>= 1) {
            #pragma unroll
            for (int i = 0; i < 4; ++i)
                acc[i] += __shfl_down(acc[i], off, 64);
        }
        if (lane == 0) {
            #pragma unroll
            for (int i = 0; i < 4; ++i)
                logits[ks[i]] = acc[i];
        }
    }
    __syncthreads();

    if (tid < 64) {
        float v = (tid < NLOGITS) ? logits[tid] : -INFINITY;
        float m = v;
        #pragma unroll
        for (int off = 32; off > 0; off >>= 1)
            m = fmaxf(m, __shfl_down(m, off, 64));
        m = __shfl(m, 0, 64);
        float e = (tid < NLOGITS) ? __expf(v - m) : 0.0f;
        #pragma unroll
        for (int off = 32; off > 0; off >>= 1)
            e += __shfl_down(e, off, 64);
        if (tid == 0) {
            float loss = m + __logf(e) - logits[0];
            atomicAdd(out, loss * (1.0f / (float)NB));
        }
    }
}

extern "C" void kernel_launch(void* const* d_in, const int* in_sizes, int n_in,
                              void* d_out, int out_size, void* d_ws, size_t ws_size,
                              hipStream_t stream) {
    const float* user  = (const float*)d_in[0];   // (B, D) fp32
    const float* items = (const float*)d_in[1];   // (B, D) fp32
    const int*   negi  = (const int*)d_in[2];     // (B, K) int32
    float* out = (float*)d_out;                   // scalar fp32

    hipMemsetAsync(out, 0, sizeof(float), stream);

    if (ws_size >= WS_NEED) {
        char* ws = (char*)d_ws;
        float*        logits = (float*)(ws + WS_LOGITS_OFF);
        unsigned int* itemsh = (unsigned int*)(ws + WS_ITEMS_OFF);

        // 786432 float4 -> 3072 blocks of 256
        convert_items_f16<<<(NB * ND / 4) / 256, 256, 0, stream>>>(
            (const f4v*)items, (uint2*)itemsh);
        // 4096 rows x 8 waves = 32768 waves = 8192 blocks of 4 waves
        gather_dots<<<NB * 8 / 4, 256, 0, stream>>>(
            user, itemsh, negi, logits);
        // 16 blocks x 256 threads; thread = row
        lse_reduce<<<NB / 256, 256, 0, stream>>>(logits, out);
    } else {
        u2i_loss_f32<<<NB, 256, 0, stream>>>(user, items, negi, out);
    }
}